// Round 7
// baseline (459.098 us; speedup 1.0000x reference)
//
#include <hip/hip_runtime.h>
#include <hip/hip_fp16.h>
#include <math.h>

// Fan-beam CT forward projection — analytic Siddon, rank merge, LDS image.
//
// R6 post-mortem: global-memory gathers are line-transaction bound and no
// row-major layout coalesces all ray angles (vertical rays hit 64 distinct
// lines/gather). Fix: stage the whole image (fp16, 128 KB) in LDS — no cache
// lines, only banks. Row stride 258 halves rotates banks +1 word/row so both
// vertical (bank step 1) and horizontal (2 lanes/word) rays are conflict-free.
// One 1024-thread block stages once and processes 64 rays (4/wave) to
// amortize staging (1035 blocks x 128 KB = 135 MB L2 reads total).

constexpr int IMG_N  = 256;
constexpr int NDET   = 368;
constexpr int NVIEW  = 180;
constexpr int NSAMP  = 2 * IMG_N + 1;       // 513
constexpr int DV     = NDET * NVIEW;        // 66240 (= 1035 * 64)
constexpr int NITER  = (NSAMP + 63) / 64;   // 9 (fallback kernel)

constexpr int LDS_STRIDE = 258;                       // halves (+1 word/row bank rot)
constexpr size_t LDS_BYTES = (size_t)IMG_N * LDS_STRIDE * 2;  // 132,096 B

struct __align__(8) Corner { __half2 ab; __half2 cd; };  // fallback path

// ws layout: region0 = max(img16 128KB, Corner 512KB) | rt: 3 float4/ray | kr: int2/ray
constexpr size_t REG0_BYTES = (size_t)IMG_N * IMG_N * sizeof(Corner); // 512 KiB
constexpr size_t RT_OFF     = REG0_BYTES;
constexpr size_t RT_BYTES   = (size_t)DV * 3 * sizeof(float4);
constexpr size_t KR_OFF     = RT_OFF + RT_BYTES;
constexpr size_t KR_BYTES   = (size_t)DV * sizeof(int2);
constexpr size_t WS_NEEDED  = KR_OFF + KR_BYTES;                      // ~4.2 MB

__device__ __forceinline__ double valAP(double A, double s, double inv, int k) {
    return (A + s * (double)k) * inv;
}

// ---- img -> flat fp16 ----
__global__ __launch_bounds__(256) void pack16_kernel(
    const float* __restrict__ img, __half* __restrict__ img16)
{
    const int i = blockIdx.x * 256 + threadIdx.x;   // 65536 total
    img16[i] = __float2half(img[i]);
}

// ---- fallback corner pack (fp16) ----
__global__ __launch_bounds__(256) void pack_kernel(
    const float* __restrict__ img, Corner* __restrict__ P)
{
    const int idx = blockIdx.x * 256 + threadIdx.x;
    const int y  = idx >> 8;
    const int x  = idx & 255;
    const int x1 = min(x + 1, IMG_N - 1);
    const int y1 = min(y + 1, IMG_N - 1);
    Corner c;
    c.ab = __floats2half2_rn(img[y * IMG_N + x],  img[y * IMG_N + x1]);
    c.cd = __floats2half2_rn(img[y1 * IMG_N + x], img[y1 * IMG_N + x1]);
    P[idx] = c;
}

// ---- per-ray geometry (fp64 membership, fp32 folded constants) ----
__global__ __launch_bounds__(256) void geom_kernel(
    float4* __restrict__ rt, int2* __restrict__ kr)
{
    const int idx = blockIdx.x * 256 + threadIdx.x;
    if (idx >= DV) return;
    const int d = idx / NVIEW;
    const int v = idx - d * NVIEW;

    const double d_beta = ((M_PI * 360.0) / (double)NVIEW) / 180.0;
    const double stop   = (double)(NVIEW - 1) * d_beta;
    const double step   = stop / (double)(NVIEW - 1);
    const double beta   = (v == NVIEW - 1) ? stop : (double)v * step;
    const double cb = cos(beta), sb = sin(beta);

    const double sx  = -500.0 * cb;
    const double sy  =  500.0 * sb;
    const double rdy = ((double)d - 183.5) * 2.0;
    const double dx  = cb * 500.0 + sb * rdy;
    const double dy  = (-sb) * 500.0 + cb * rdy;
    const double ddx = dx - sx, ddy = dy - sy;

    double Ax, sxn;
    const double invx = 1.0 / ddx;
    if (invx >= 0.0) { Ax = -128.0 - sx; sxn = 1.0; }
    else             { Ax =  128.0 - sx; sxn = -1.0; }
    double Ay, syn;
    const double invy = 1.0 / ddy;
    if (invy >= 0.0) { Ay = -128.0 - sy; syn = 1.0; }
    else             { Ay =  128.0 - sy; syn = -1.0; }

    const double vx0 = valAP(Ax, sxn, invx, 0), vxN = valAP(Ax, sxn, invx, IMG_N);
    const double vy0 = valAP(Ay, syn, invy, 0), vyN = valAP(Ay, syn, invy, IMG_N);
    double a_min = fmax(vx0, vy0); if (a_min < 0.0) a_min = 0.0;
    double a_max = fmin(vxN, vyN); if (a_max > 1.0) a_max = 1.0;

    const double absdx = fabs(ddx), absdy = fabs(ddy);

    int klox, khix, kloy, khiy;
    {
        double kd = (a_min - vx0) * absdx;
        kd = fmin(fmax(kd, -1.0), 258.0);
        int k = (int)kd; k = max(0, min(k, 256));
        while (k > 0    && valAP(Ax, sxn, invx, k - 1) >= a_min) --k;
        while (k <= 256 && valAP(Ax, sxn, invx, k) < a_min)      ++k;
        klox = k;
        kd = (a_max - vx0) * absdx;
        kd = fmin(fmax(kd, -1.0), 258.0);
        k = (int)kd; k = max(0, min(k, 256));
        while (k > 0    && valAP(Ax, sxn, invx, k - 1) > a_max)  --k;
        while (k <= 256 && valAP(Ax, sxn, invx, k) <= a_max)     ++k;
        khix = k - 1;
        if (klox > khix) { klox = 0; khix = -1; }
    }
    {
        double kd = (a_min - vy0) * absdy;
        kd = fmin(fmax(kd, -1.0), 258.0);
        int k = (int)kd; k = max(0, min(k, 256));
        while (k > 0    && valAP(Ay, syn, invy, k - 1) >= a_min) --k;
        while (k <= 256 && valAP(Ay, syn, invy, k) < a_min)      ++k;
        kloy = k;
        kd = (a_max - vy0) * absdy;
        kd = fmin(fmax(kd, -1.0), 258.0);
        k = (int)kd; k = max(0, min(k, 256));
        while (k > 0    && valAP(Ay, syn, invy, k - 1) > a_max)  --k;
        while (k <= 256 && valAP(Ay, syn, invy, k) <= a_max)     ++k;
        khiy = k - 1;
        if (kloy > khiy) { kloy = 0; khiy = -1; }
    }

    const int nx = khix - klox + 1;
    const int ny = khiy - kloy + 1;
    const double s2d = sqrt(ddx * ddx + ddy * ddy);

    const double sxd = sxn * invx, syd = syn * invy;           // both > 0
    const double bxd = (Ax + sxn * (double)klox) * invx;
    const double byd = (Ay + syn * (double)kloy) * invy;
    const double ssum = sxd + syd;
    const double c0 = (byd - bxd) / ssum;
    const double c1 = syd / ssum;

    float4* o = rt + (size_t)idx * 3;
    o[0] = make_float4((float)bxd, (float)sxd, (float)byd, (float)syd);
    o[1] = make_float4((float)c0, (float)c1, (float)s2d, 0.0f);
    o[2] = make_float4((float)(ddx * (128.0 / 127.5)),
                       (float)(sx  * (128.0 / 127.5) + 127.5),
                       (float)(ddy * (128.0 / 127.5)),
                       (float)(sy  * (128.0 / 127.5) + 127.5));
    kr[idx] = make_int2(nx, ny);
}

// merged(q): q-th smallest (0-based) of X[0..nx) U Y[0..ny), ascending APs.
__device__ __forceinline__ float mergedq(int q, float bx, float sx, float by,
                                         float sy, float c0, float c1,
                                         int nx, int ny)
{
    const int t   = q + 1;
    const int mlo = max(0, t - ny);
    const int mhi = min(nx, t);
    int m = (int)fmaf((float)q, c1, c0);
    m = max(mlo, min(m, mhi));
    while (m > mlo) {
        const int mm = m - 1;
        const bool Pmm = (t - 1 - mm < 0) || (mm >= nx) ||
            (fmaf((float)(t - 1 - mm), sy, by) <= fmaf((float)mm, sx, bx));
        if (!Pmm) break;
        m = mm;
    }
    while (m < mhi) {
        const bool Pm = (t - 1 - m < 0) || (m >= nx) ||
            (fmaf((float)(t - 1 - m), sy, by) <= fmaf((float)m, sx, bx));
        if (Pm) break;
        ++m;
    }
    const float xl = (m > 0)     ? fmaf((float)(m - 1),     sx, bx) : -3e38f;
    const float yl = (t - m > 0) ? fmaf((float)(t - 1 - m), sy, by) : -3e38f;
    return fmaxf(xl, yl);
}

// ---- main: 1024-thread block, LDS image, 64 rays/block (4 per wave) ----
__global__ __launch_bounds__(1024) void fp_siddon_lds(
    const __half* __restrict__ img16,
    const float4* __restrict__ rt,
    const int2*   __restrict__ kr,
    float*        __restrict__ out)
{
    extern __shared__ __half simg[];   // [256][258] halves
    const int tid = threadIdx.x;

    // stage: 32768 uints (2 halves each), coalesced reads, 2-way-free writes
    {
        const unsigned* src = (const unsigned*)img16;
        #pragma unroll
        for (int i = 0; i < 32; ++i) {
            const int u = i * 1024 + tid;
            const unsigned val = src[u];
            const int p = u * 2;             // pixel index (even)
            const int y = p >> 8;
            const int x = p & 255;
            *reinterpret_cast<unsigned*>(&simg[y * LDS_STRIDE + x]) = val;
        }
    }
    __syncthreads();

    const int wave = tid >> 6;
    const int lane = tid & 63;

    for (int r = 0; r < 4; ++r) {
        const int dv = __builtin_amdgcn_readfirstlane(blockIdx.x * 64 + wave * 4 + r);

        const float4 A = rt[(size_t)dv * 3 + 0];   // bx, sx, by, sy
        const float4 B = rt[(size_t)dv * 3 + 1];   // c0, c1, s2d
        const float4 C = rt[(size_t)dv * 3 + 2];   // cxa, cxb, cya, cyb
        const int2 nn = kr[dv];
        const int nx = nn.x, ny = nn.y;
        const int npairs = nx + ny - 1;

        float acc = 0.0f;

        for (int base = 0; base < npairs; base += 64) {
            const int p = base + lane;
            const bool act = (p < npairs);
            const int q = act ? p + 1 : 1;

            const float cur = mergedq(q, A.x, A.y, A.z, A.w, B.x, B.y, nx, ny);
            float prev = __shfl_up(cur, 1, 64);
            if (lane == 0)
                prev = mergedq(base, A.x, A.y, A.z, A.w, B.x, B.y, nx, ny);

            const float diff = cur - prev;
            const float mid  = fmaf(diff, 0.5f, prev);
            const float ixp  = fmaf(mid, C.x, C.y);
            const float iyp  = fmaf(mid, C.z, C.w);
            const float wf   = act ? diff * B.z : 0.0f;

            const float fx0 = floorf(ixp), fy0 = floorf(iyp);
            const float wx1 = ixp - fx0,  wy1 = iyp - fy0;
            const int x0 = (int)fx0, y0 = (int)fy0;

            const int xc0 = min(max(x0, 0), IMG_N - 1);
            const int xc1 = min(max(x0 + 1, 0), IMG_N - 1);
            const int hb0 = min(max(y0, 0), IMG_N - 1) * LDS_STRIDE;
            const int hb1 = min(max(y0 + 1, 0), IMG_N - 1) * LDS_STRIDE;

            const float v00 = __half2float(simg[hb0 + xc0]);
            const float v01 = __half2float(simg[hb0 + xc1]);
            const float v10 = __half2float(simg[hb1 + xc0]);
            const float v11 = __half2float(simg[hb1 + xc1]);

            const float x0v = (((unsigned)x0)       < 256u) ? 1.0f : 0.0f;
            const float x1v = (((unsigned)(x0 + 1)) < 256u) ? 1.0f : 0.0f;
            const float my0 = (((unsigned)y0)       < 256u) ? 1.0f : 0.0f;
            const float my1 = (((unsigned)(y0 + 1)) < 256u) ? 1.0f : 0.0f;
            const float wx0 = 1.0f - wx1;
            const float wy0 = (1.0f - wy1) * my0;
            const float wy1m = wy1 * my1;
            const float interp = (v00 * x0v * wx0 + v01 * x1v * wx1) * wy0
                               + (v10 * x0v * wx0 + v11 * x1v * wx1) * wy1m;

            acc = fmaf(wf, interp, acc);
        }

        #pragma unroll
        for (int off = 32; off > 0; off >>= 1)
            acc += __shfl_down(acc, off, 64);
        if (lane == 0)
            out[dv] = isnan(acc) ? 0.0f : acc;
    }
}

// ---- fallback: R6 global-gather rank-merge kernel ----
__global__ __launch_bounds__(256) void fp_siddon(
    const Corner* __restrict__ P,
    const float4* __restrict__ rt,
    const int2*   __restrict__ kr,
    float*        __restrict__ out)
{
    const int wave = threadIdx.x >> 6;
    const int lane = threadIdx.x & 63;
    const int dv   = __builtin_amdgcn_readfirstlane(blockIdx.x * 4 + wave);

    const float4 A = rt[(size_t)dv * 3 + 0];
    const float4 B = rt[(size_t)dv * 3 + 1];
    const float4 C = rt[(size_t)dv * 3 + 2];
    const int2 nn = kr[dv];
    const int nx = nn.x, ny = nn.y;
    const int npairs = nx + ny - 1;

    float acc = 0.0f;
    for (int base = 0; base < npairs; base += 64) {
        const int p = base + lane;
        const bool act = (p < npairs);
        const int q = act ? p + 1 : 1;
        const float cur = mergedq(q, A.x, A.y, A.z, A.w, B.x, B.y, nx, ny);
        float prev = __shfl_up(cur, 1, 64);
        if (lane == 0)
            prev = mergedq(base, A.x, A.y, A.z, A.w, B.x, B.y, nx, ny);
        const float diff = cur - prev;
        const float mid  = fmaf(diff, 0.5f, prev);
        const float ixp  = fmaf(mid, C.x, C.y);
        const float iyp  = fmaf(mid, C.z, C.w);
        const float wf   = act ? diff * B.z : 0.0f;
        const float fx0 = floorf(ixp), fy0 = floorf(iyp);
        const float wx1 = ixp - fx0,  wy1 = iyp - fy0;
        const int x0 = (int)fx0, y0 = (int)fy0;
        const int xc = min(max(x0, 0), IMG_N - 1);
        const int yb = min(max(y0, 0), IMG_N - 1);
        const Corner pc = P[yb * IMG_N + xc];
        const float2 r0 = __half22float2(pc.ab);
        const float2 r1 = __half22float2(pc.cd);
        const bool loX = (x0 == -1), loY = (y0 == -1);
        const float a  = r0.x;
        const float b2 = loX ? r0.x : r0.y;
        const float d2 = loX ? r1.x : r1.y;
        const float c3 = loY ? a  : r1.x;
        const float d3 = loY ? b2 : d2;
        const float x0v = (((unsigned)x0)       < 256u) ? 1.0f : 0.0f;
        const float x1v = (((unsigned)(x0 + 1)) < 256u) ? 1.0f : 0.0f;
        const float my0 = (((unsigned)y0)       < 256u) ? 1.0f : 0.0f;
        const float my1 = (((unsigned)(y0 + 1)) < 256u) ? 1.0f : 0.0f;
        const float wx0 = 1.0f - wx1;
        const float wy0 = (1.0f - wy1) * my0;
        const float wy1m = wy1 * my1;
        const float interp = (a * x0v * wx0 + b2 * x1v * wx1) * wy0
                           + (c3 * x0v * wx0 + d3 * x1v * wx1) * wy1m;
        acc = fmaf(wf, interp, acc);
    }
    #pragma unroll
    for (int off = 32; off > 0; off >>= 1)
        acc += __shfl_down(acc, off, 64);
    if (lane == 0)
        out[dv] = isnan(acc) ? 0.0f : acc;
}

// ---- last-resort fallback (ws too small): stream-reading kernel ----
__global__ __launch_bounds__(256) void fp_kernel_nopack(
    const float*  __restrict__ img,
    const float2* __restrict__ grid,
    const float*  __restrict__ wt,
    float*        __restrict__ out)
{
    const int wave = threadIdx.x >> 6;
    const int lane = threadIdx.x & 63;
    const int dv   = blockIdx.x * 4 + wave;
    const long base = (long)dv * NSAMP;

    float2 g[NITER];
    float  w[NITER];
    #pragma unroll
    for (int k = 0; k < NITER; ++k) {
        const int s = lane + k * 64;
        if (s < NSAMP) { g[k] = grid[base + s]; w[k] = wt[base + s]; }
        else           { g[k] = make_float2(0.0f, 0.0f); w[k] = 0.0f; }
    }
    float acc = 0.0f;
    #pragma unroll
    for (int k = 0; k < NITER; ++k) {
        const float ix = ((g[k].x + 1.0f) * 256.0f - 1.0f) * 0.5f;
        const float iy = ((g[k].y + 1.0f) * 256.0f - 1.0f) * 0.5f;
        const float fx0 = floorf(ix), fy0 = floorf(iy);
        const float wx1 = ix - fx0,  wy1 = iy - fy0;
        const int x0 = (int)fx0, y0 = (int)fy0;
        const int xc  = min(max(x0, 0), IMG_N - 2);
        const int yc0 = min(max(y0, 0), IMG_N - 1);
        const int yc1 = min(max(y0 + 1, 0), IMG_N - 1);
        const float2 p0 = *(const float2*)(img + yc0 * IMG_N + xc);
        const float2 p1 = *(const float2*)(img + yc1 * IMG_N + xc);
        const bool x0v = ((unsigned)x0) < 256u;
        const bool x1v = ((unsigned)(x0 + 1)) < 256u;
        const bool hiX = (x0 == IMG_N - 1);
        const bool loX = (x0 == -1);
        const float v00 = x0v ? (hiX ? p0.y : p0.x) : 0.0f;
        const float v01 = x1v ? (loX ? p0.x : p0.y) : 0.0f;
        const float v10 = x0v ? (hiX ? p1.y : p1.x) : 0.0f;
        const float v11 = x1v ? (loX ? p1.x : p1.y) : 0.0f;
        const float my0 = (((unsigned)y0) < 256u) ? 1.0f : 0.0f;
        const float my1 = (((unsigned)(y0 + 1)) < 256u) ? 1.0f : 0.0f;
        const float wx0 = 1.0f - wx1;
        const float wy0 = (1.0f - wy1) * my0;
        const float wy1m = wy1 * my1;
        acc += w[k] * ((v00 * wx0 + v01 * wx1) * wy0
                     + (v10 * wx0 + v11 * wx1) * wy1m);
    }
    #pragma unroll
    for (int off = 32; off > 0; off >>= 1)
        acc += __shfl_down(acc, off, 64);
    if (lane == 0) out[dv] = isnan(acc) ? 0.0f : acc;
}

extern "C" void kernel_launch(void* const* d_in, const int* in_sizes, int n_in,
                              void* d_out, int out_size, void* d_ws, size_t ws_size,
                              hipStream_t stream) {
    const float*  img  = (const float*)d_in[0];
    const float2* grid = (const float2*)d_in[1];
    const float*  wt   = (const float*)d_in[2];
    float*        out  = (float*)d_out;

    if (ws_size >= WS_NEEDED) {
        float4* rt = (float4*)((char*)d_ws + RT_OFF);
        int2*   kr = (int2*)  ((char*)d_ws + KR_OFF);

        // Can this device give one workgroup 132 KB of LDS? (gfx950: 160 KB/CU)
        int dev = 0, smemCU = 0;
        hipGetDevice(&dev);
        hipDeviceGetAttribute(&smemCU,
            hipDeviceAttributeMaxSharedMemoryPerMultiprocessor, dev);

        if ((size_t)smemCU >= LDS_BYTES) {
            __half* img16 = (__half*)d_ws;
            (void)hipFuncSetAttribute((const void*)fp_siddon_lds,
                hipFuncAttributeMaxDynamicSharedMemorySize, (int)LDS_BYTES);
            pack16_kernel<<<IMG_N * IMG_N / 256, 256, 0, stream>>>(img, img16);
            geom_kernel<<<(DV + 255) / 256, 256, 0, stream>>>(rt, kr);
            fp_siddon_lds<<<DV / 64, 1024, LDS_BYTES, stream>>>(img16, rt, kr, out);
        } else {
            Corner* P = (Corner*)d_ws;
            pack_kernel<<<IMG_N * IMG_N / 256, 256, 0, stream>>>(img, P);
            geom_kernel<<<(DV + 255) / 256, 256, 0, stream>>>(rt, kr);
            fp_siddon<<<DV / 4, 256, 0, stream>>>(P, rt, kr, out);
        }
    } else {
        fp_kernel_nopack<<<DV / 4, 256, 0, stream>>>(img, grid, wt, out);
    }
}